// Round 10
// baseline (434.536 us; speedup 1.0000x reference)
//
#include <hip/hip_runtime.h>
#include <math.h>
#include <cstddef>

// Problem constants
#define BB 2
#define TT 2048
#define CC 2048
#define HH 16
#define HD 128
#define MM (BB * TT)   // 4096 tokens
#define QKV_N 6144
#define BK 32

typedef __attribute__((ext_vector_type(8))) short short8;
typedef __attribute__((ext_vector_type(4))) float f32x4;

__device__ __forceinline__ unsigned short f2bf(float f) {
    union { float f; unsigned int u; } v; v.f = f;
    unsigned int r = v.u + 0x7FFFu + ((v.u >> 16) & 1u);  // RNE
    return (unsigned short)(r >> 16);
}
// 2-op nearest-half-up convert for the attn exp path (P > 0 always).
// R14's v_cvt_pk_bf16_f32 TRUNCATES on gfx950 (absmax 0.07) — do not use.
__device__ __forceinline__ unsigned short f2bf_up(float f) {
    union { float f; unsigned int u; } v; v.f = f;
    return (unsigned short)((v.u + 0x8000u) >> 16);
}
__device__ __forceinline__ float bf2f(unsigned short s) {
    union { unsigned int u; float f; } v; v.u = ((unsigned int)s) << 16;
    return v.f;
}
__device__ __forceinline__ void gload16(const void* g, void* l) {
    __builtin_amdgcn_global_load_lds(
        (const __attribute__((address_space(1))) unsigned int*)g,
        (__attribute__((address_space(3))) unsigned int*)l, 16, 0, 0);
}

// ---------------------------------------------------------------------------
// K1'': fused gate + W_qkv convert + LAST-BLOCK bucket. Blocks [0,4096) run
// the gate body; [4096,10240) the convert body. R19: the last gate block to
// finish (device-scope atomic counter, threadfence release/acquire) runs the
// bucket body inline — removes the 1-block bucket kernel's serial time and
// one launch gap. No block waits (deadlock-free, dispatch-order-free).
// ---------------------------------------------------------------------------
__global__ __launch_bounds__(256) void gate_convert(const float* __restrict__ x,
                                                    const float* __restrict__ Wg,
                                                    int* __restrict__ idxbuf,
                                                    float* __restrict__ top1buf,
                                                    unsigned short* __restrict__ xb,
                                                    const float* __restrict__ Wqkv,
                                                    unsigned short* __restrict__ wb,
                                                    int* __restrict__ ord,
                                                    int* __restrict__ hs,
                                                    int* __restrict__ cnt) {
    int tid = threadIdx.x;
    if (blockIdx.x >= 4096) {
        // ---- convert path ----
        int i = (blockIdx.x - 4096) * 256 + tid;
        const float4* s4 = (const float4*)Wqkv;
        float4 a = s4[i * 2], b = s4[i * 2 + 1];
        union { unsigned short s[8]; uint4 u; } pk;
        pk.s[0] = f2bf(a.x); pk.s[1] = f2bf(a.y); pk.s[2] = f2bf(a.z); pk.s[3] = f2bf(a.w);
        pk.s[4] = f2bf(b.x); pk.s[5] = f2bf(b.y); pk.s[6] = f2bf(b.z); pk.s[7] = f2bf(b.w);
        ((uint4*)wb)[i] = pk.u;
        return;
    }
    // ---- gate path ----
    __shared__ float logits[HH];
    __shared__ int amLast;
    __shared__ unsigned short cnts[256][16];
    __shared__ int hsum[16], hbase[16];
    int m = blockIdx.x;
    int h = tid >> 4;
    int j = tid & 15;
    const float4* xr = (const float4*)(x + (size_t)m * CC);
    const float4* wr = (const float4*)(Wg + (size_t)h * CC);
    float acc = 0.f;
#pragma unroll 8
    for (int i = 0; i < CC / 4; i += 16) {
        float4 a = xr[i + j];
        float4 b = wr[i + j];
        acc += a.x * b.x + a.y * b.y + a.z * b.z + a.w * b.w;
    }
    for (int off = 8; off > 0; off >>= 1) acc += __shfl_down(acc, off, 16);
    if (j == 0) logits[h] = acc;
    // fused bf16 conversion of this token row (L1-hot re-read)
    {
        float4 a = xr[tid * 2], b = xr[tid * 2 + 1];
        union { unsigned short s[8]; uint4 u; } pk;
        pk.s[0] = f2bf(a.x); pk.s[1] = f2bf(a.y); pk.s[2] = f2bf(a.z); pk.s[3] = f2bf(a.w);
        pk.s[4] = f2bf(b.x); pk.s[5] = f2bf(b.y); pk.s[6] = f2bf(b.z); pk.s[7] = f2bf(b.w);
        ((uint4*)(xb + (size_t)m * CC))[tid] = pk.u;
    }
    __syncthreads();
    if (tid == 0) {
        float zmax = logits[0];
        int best = 0;
        for (int i = 1; i < HH; i++) {
            if (logits[i] > zmax) { zmax = logits[i]; best = i; }
        }
        float s = 0.f;
        for (int i = 0; i < HH; i++) s += expf(logits[i] - zmax);
        idxbuf[m] = best;
        top1buf[m] = 1.0f / s;
        __threadfence();                       // release: idxb visible device-wide
        int old = atomicAdd(cnt, 1);           // device-scope (m20)
        amLast = (old == 4095);
    }
    __syncthreads();
    if (!amLast) return;
    // ---- bucket body (last gate block only; all idxb written) ----
    __threadfence();                           // acquire: see other blocks' idxb
    {
        int t = tid;
        unsigned short c[16];
#pragma unroll
        for (int hh = 0; hh < 16; hh++) c[hh] = 0;
        int hv[16];
#pragma unroll
        for (int i = 0; i < 16; i++) {
            hv[i] = idxbuf[t * 16 + i];
            c[hv[i]]++;
        }
#pragma unroll
        for (int hh = 0; hh < 16; hh++) cnts[t][hh] = c[hh];
        __syncthreads();
        if (t < 16) {
            int s = 0;
            for (int jj = 0; jj < 256; jj++) {
                int v = cnts[jj][t];
                cnts[jj][t] = (unsigned short)s;
                s += v;
            }
            hsum[t] = s;
        }
        __syncthreads();
        if (t == 0) {
            int s = 0;
            for (int hh = 0; hh < 16; hh++) { hbase[hh] = s; hs[hh] = s; s += hsum[hh]; }
            hs[16] = s;
        }
        __syncthreads();
        int pos[16];
#pragma unroll
        for (int hh = 0; hh < 16; hh++) pos[hh] = hbase[hh] + (int)cnts[t][hh];
#pragma unroll
        for (int i = 0; i < 16; i++) {
            int hh = hv[i];
            ord[pos[hh]++] = t * 16 + i;
        }
    }
}

// ---------------------------------------------------------------------------
// K3': fused qproj + kvsel GEMMs (R18-validated). Blocks [0,512) = qproj
// tile; [512,2560) = kvsel slot. 2-phase double-buffered staging.
// ---------------------------------------------------------------------------
__global__ __launch_bounds__(256) void qkv_gemm(const unsigned short* __restrict__ A,   // xb [M][2048]
                                                const unsigned short* __restrict__ Bm,  // wb [6144][2048]
                                                unsigned short* __restrict__ C,         // qbuf [M][2048]
                                                const int* __restrict__ ord,
                                                const int* __restrict__ hs,
                                                const float* __restrict__ top1,
                                                unsigned short* __restrict__ kshB,
                                                unsigned short* __restrict__ vshT) {
    __shared__ unsigned short ShA[2][128 * BK];
    __shared__ unsigned short ShB[2][128 * BK];
    int tid = threadIdx.x;
    int wave = tid >> 6, lane = tid & 63;
    int l = lane & 15, g = lane >> 4;
    int flat = blockIdx.x;

    if (flat < 512) {
        // ================= qproj path =================
        int m0 = (flat >> 4) * 128, n0 = (flat & 15) * 128;
        int wr = wave >> 1, wc = wave & 1;

        f32x4 acc[4][4];
#pragma unroll
        for (int i = 0; i < 4; i++)
#pragma unroll
            for (int j = 0; j < 4; j++) acc[i][j] = (f32x4){0.f, 0.f, 0.f, 0.f};

        int srow = lane >> 2;
        int scol = (lane & 3) * 8;
        const unsigned short* aB0 = A + (size_t)(m0 + wave * 32 + srow) * 2048 + scol;
        const unsigned short* bB0 = Bm + (size_t)(n0 + wave * 32 + srow) * 2048 + scol;

#define QSTAGE(k0_, bi) do {                                                    \
        gload16(aB0 + (k0_), &ShA[bi][wave * 1024]);                            \
        gload16(aB0 + (k0_) + (size_t)16 * 2048, &ShA[bi][wave * 1024 + 512]);  \
        gload16(bB0 + (k0_), &ShB[bi][wave * 1024]);                            \
        gload16(bB0 + (k0_) + (size_t)16 * 2048, &ShB[bi][wave * 1024 + 512]);  \
    } while (0)

        QSTAGE(0, 0);
        __syncthreads();

        for (int k0 = 0; k0 < 2048; k0 += BK) {
            int cur = (k0 >> 5) & 1;
            if (k0 + BK < 2048) QSTAGE(k0 + BK, cur ^ 1);
            short8 af[4], bf[4];
#pragma unroll
            for (int i = 0; i < 4; i++)
                af[i] = *(const short8*)&ShA[cur][(wr * 64 + i * 16 + l) * BK + g * 8];
#pragma unroll
            for (int j = 0; j < 4; j++)
                bf[j] = *(const short8*)&ShB[cur][(wc * 64 + j * 16 + l) * BK + g * 8];
#pragma unroll
            for (int i = 0; i < 4; i++)
#pragma unroll
                for (int j = 0; j < 4; j++)
                    acc[i][j] = __builtin_amdgcn_mfma_f32_16x16x32_bf16(af[i], bf[j], acc[i][j], 0, 0, 0);
            __syncthreads();
        }
#undef QSTAGE

        const float qscale = 0.08838834764831845f;  // 1/sqrt(128)
#pragma unroll
        for (int j = 0; j < 4; j++) {
            int col = n0 + wc * 64 + j * 16 + l;
#pragma unroll
            for (int i = 0; i < 4; i++) {
                int row = m0 + wr * 64 + i * 16 + g * 4;
#pragma unroll
                for (int r = 0; r < 4; r++)
                    C[(size_t)(row + r) * CC + col] = f2bf(acc[i][j][r] * qscale);
            }
        }
        return;
    }

    // ================= kvsel path =================
    {
        int kv = flat - 512;
        int h = kv & 15, reg = (kv >> 4) & 1, mt = kv >> 5;
        int s0 = hs[h], s1 = hs[h + 1];
        int cnt = s1 - s0;
        if (mt * 64 >= cnt) return;
        int base = s0 + mt * 64;

        int arow = base + wave * 16 + (lane >> 2);
        int atok = ord[(arow < s1) ? arow : (s1 - 1)];
        const unsigned short* aSrc = A + (size_t)atok * CC + (lane & 3) * 8;
        int wr0 = 2048 + reg * 2048 + h * 128;
        const unsigned short* bSrc0 = Bm + (size_t)(wr0 + (wave * 2 + 0) * 16 + (lane >> 2)) * CC + (lane & 3) * 8;
        const unsigned short* bSrc1 = Bm + (size_t)(wr0 + (wave * 2 + 1) * 16 + (lane >> 2)) * CC + (lane & 3) * 8;

#define KSTAGE(k0_, bi) do {                                      \
        gload16(aSrc + (k0_), &ShA[bi][wave * 512]);              \
        gload16(bSrc0 + (k0_), &ShB[bi][(wave * 2 + 0) * 512]);   \
        gload16(bSrc1 + (k0_), &ShB[bi][(wave * 2 + 1) * 512]);   \
    } while (0)

        f32x4 acc[8];
#pragma unroll
        for (int j = 0; j < 8; j++) acc[j] = (f32x4){0.f, 0.f, 0.f, 0.f};

        KSTAGE(0, 0);
        __syncthreads();

        for (int k0 = 0; k0 < 2048; k0 += 32) {
            int cur = (k0 >> 5) & 1;
            if (k0 + 32 < 2048) KSTAGE(k0 + 32, cur ^ 1);
            short8 af = *(const short8*)&ShA[cur][(wave * 16 + l) * 32 + g * 8];
#pragma unroll
            for (int j = 0; j < 8; j++) {
                short8 bf = *(const short8*)&ShB[cur][(j * 16 + l) * 32 + g * 8];
                acc[j] = __builtin_amdgcn_mfma_f32_16x16x32_bf16(af, bf, acc[j], 0, 0, 0);
            }
            __syncthreads();
        }
#undef KSTAGE

#pragma unroll
        for (int i = 0; i < 4; i++) {
            int r = wave * 16 + g * 4 + i;
            if (base + r >= s1) continue;
            int tok = ord[base + r];
            if (reg == 0) {
#pragma unroll
                for (int j = 0; j < 8; j++)
                    kshB[(size_t)tok * HD + j * 16 + l] = f2bf(acc[j][i]);
            } else {
                float tv = top1[tok];
#pragma unroll
                for (int j = 0; j < 8; j++)
                    vshT[(size_t)(j * 16 + l) * MM + tok] = f2bf(acc[j][i] * tv);
            }
        }
    }
}

// ---------------------------------------------------------------------------
// K6: MFMA bf16 flash attention — R17 structure (unpaired q-tiles, 1024
// blocks, 4 blocks/CU) + R19 T5 setprio(1) around MFMA clusters: with 4
// barrier-phased blocks/CU the waves have role diversity (load-issuing vs
// MFMA-entering), the regime where setprio paid +4-7% on attn (m191).
// ---------------------------------------------------------------------------
__global__ __launch_bounds__(256, 4) void attn_mfma(const unsigned short* __restrict__ qb,   // [M][2048] bf16, q pre-scaled
                                                    const unsigned short* __restrict__ kb,   // [M][128] bf16
                                                    const unsigned short* __restrict__ vtb,  // [128][M] bf16
                                                    float* __restrict__ y) {                 // [M][2048] fp32
    __shared__ unsigned short KsA[2][32 * 128];   // 16384 B, linear, swizzled content
    __shared__ unsigned short VtA[2][128 * 32];   // 16384 B, linear, swizzled content
    __shared__ unsigned short Ps[4][16][40];      // 5120 B (per-wave)

    int bid = blockIdx.x;                 // 1024 blocks
    // boustrophedon descending-workload rank
    int t = bid & 255, r = bid >> 8;
    int k = (r << 8) | ((r & 1) ? (255 - t) : t);
    int qi = 127 - (k >> 3);              // q-tile 127..0 (long first)
    int b  = (k >> 2) & 1;
    int hq = k & 3;                       // head quarter
    int q0 = qi * 16;
    int nch = (qi >> 1) + 1;              // 1..64 32-key chunks
    int tid = threadIdx.x;
    int wave = tid >> 6;
    int lane = tid & 63;
    int l = lane & 15;
    int g = lane >> 4;
    int h = hq * 4 + wave;                // one head per wave

    // Q a-frags (bf16, pre-scaled)
    short8 qf[4];
    {
        const unsigned short* qrow = qb + (size_t)(b * TT + q0 + l) * CC + h * HD;
#pragma unroll
        for (int kc = 0; kc < 4; kc++)
            qf[kc] = *(const short8*)(qrow + kc * 32 + g * 8);
    }

    // ones-column B-frag: B[n][k] = (n==0) ? 1 : 0
    short8 onesf;
    {
        short v = (l == 0) ? (short)0x3F80 : (short)0;
#pragma unroll
        for (int e = 0; e < 8; e++) onesf[e] = v;
    }

    f32x4 o[8];
    f32x4 o8 = (f32x4){0.f, 0.f, 0.f, 0.f};
#pragma unroll
    for (int n = 0; n < 8; n++) o[n] = (f32x4){0.f, 0.f, 0.f, 0.f};

    const unsigned short* kbase = kb + (size_t)b * TT * HD;
    int rbase = q0 + g * 4;

    // Staging: 512 16B slots each for K and V; thread stages slots tid, tid+256.
    // K slot s: row r=s>>4 (key), physical chunk p=s&15; holds global chunk p^(r&15).
    // V slot s: row d=s>>2 (dim), physical chunk p=s&3; holds global chunk p^((d>>1)&3).
    // global_load_lds writes lane i at (uniform base + i*16) -> linear slot order.
#define STAGE(cc, bufi) do {                                                      \
        int kc0_ = (cc) * 32;                                                     \
        _Pragma("unroll")                                                         \
        for (int rep_ = 0; rep_ < 2; rep_++) {                                    \
            int s_ = tid + rep_ * 256;                                            \
            int kr_ = s_ >> 4, kp_ = s_ & 15;                                     \
            gload16(kbase + (size_t)(kc0_ + kr_) * HD + ((kp_ ^ (kr_ & 15)) * 8), \
                    &KsA[bufi][(rep_ * 256 + wave * 64) * 8]);                    \
            int vd_ = s_ >> 2, vp_ = s_ & 3;                                      \
            int vq_ = vp_ ^ ((vd_ >> 1) & 3);                                     \
            gload16(vtb + (size_t)vd_ * MM + b * TT + kc0_ + vq_ * 8,             \
                    &VtA[bufi][(rep_ * 256 + wave * 64) * 8]);                    \
        }                                                                         \
    } while (0)

    STAGE(0, 0);
    __syncthreads();   // drains the prologue staging (vmcnt(0) inside)

    for (int c = 0; c < nch; c++) {
        int kc0 = c * 32;
        int cur = c & 1;
        if (c + 1 < nch) STAGE(c + 1, cur ^ 1);   // prefetch flies during compute
        bool diag = (c == nch - 1);
        const unsigned short* Kc = KsA[cur];
        const unsigned short* Vc = VtA[cur];

        // S = Q K^T over 2 key-tiles of 16.
#pragma unroll
        for (int tt = 0; tt < 2; tt++) {
            short8 kf[4];
#pragma unroll
            for (int kc = 0; kc < 4; kc++)
                kf[kc] = *(const short8*)&Kc[(tt * 16 + l) * 128 + (((kc * 4 + g) ^ l) * 8)];
            f32x4 sl = (f32x4){0.f, 0.f, 0.f, 0.f};
            __builtin_amdgcn_s_setprio(1);
#pragma unroll
            for (int kc = 0; kc < 4; kc++)
                sl = __builtin_amdgcn_mfma_f32_16x16x32_bf16(qf[kc], kf[kc], sl, 0, 0, 0);
            __builtin_amdgcn_s_setprio(0);
            if (diag) {
                int key = kc0 + tt * 16 + l;
#pragma unroll
                for (int i = 0; i < 4; i++)
                    if (key > rbase + i) sl[i] = -1e30f;
            }
#pragma unroll
            for (int i = 0; i < 4; i++)
                Ps[wave][g * 4 + i][tt * 16 + l] = f2bf_up(__expf(sl[i] - 30.f));
        }
        // O += P V ; l += P.
        {
            short8 pf0 = *(const short8*)&Ps[wave][l][g * 8];
            __builtin_amdgcn_s_setprio(1);
#pragma unroll
            for (int n = 0; n < 8; n++) {
                short8 vf = *(const short8*)&Vc[(n * 16 + l) * 32 + ((g ^ ((l >> 1) & 3)) * 8)];
                o[n] = __builtin_amdgcn_mfma_f32_16x16x32_bf16(pf0, vf, o[n], 0, 0, 0);
            }
            o8 = __builtin_amdgcn_mfma_f32_16x16x32_bf16(pf0, onesf, o8, 0, 0, 0);
            __builtin_amdgcn_s_setprio(0);
        }
        __syncthreads();   // vmcnt(0)+lgkmcnt(0) drain AFTER compute: prefetch done,
                           // and all waves finished reading buf[cur] before next overwrite
    }
#undef STAGE

    // epilogue: normalize; l for row g*4+i sits in lane (g*16, reg i)
    {
        float inv[4];
#pragma unroll
        for (int i = 0; i < 4; i++) {
            float lv = __shfl(o8[i], lane & 48);
            inv[i] = 1.f / lv;
        }
#pragma unroll
        for (int n = 0; n < 8; n++) {
#pragma unroll
            for (int i = 0; i < 4; i++) {
                y[(size_t)(b * TT + q0 + g * 4 + i) * CC + h * HD + n * 16 + l] =
                    o[n][i] * inv[i];
            }
        }
    }
}

// ---------------------------------------------------------------------------
// Launcher. Workspace (~62 MB). 3 launches + 1 tiny memset (counter reset).
// ---------------------------------------------------------------------------
extern "C" void kernel_launch(void* const* d_in, const int* in_sizes, int n_in,
                              void* d_out, int out_size, void* d_ws, size_t ws_size,
                              hipStream_t stream) {
    (void)in_sizes; (void)n_in; (void)out_size; (void)ws_size;
    const float* x    = (const float*)d_in[0];
    const float* Wg   = (const float*)d_in[1];
    const float* Wqkv = (const float*)d_in[2];
    float* y = (float*)d_out;

    unsigned short* xb   = (unsigned short*)d_ws;
    unsigned short* wb   = xb + (size_t)MM * CC;
    unsigned short* qbuf = wb + (size_t)QKV_N * CC;
    unsigned short* kshB = qbuf + (size_t)MM * CC;
    unsigned short* vshT = kshB + (size_t)MM * HD;
    float* top1 = (float*)(vshT + (size_t)HD * MM);
    int*   idxb = (int*)(top1 + MM);
    int*   ord  = idxb + MM;
    int*   hs   = ord + MM;
    int*   cntr = hs + 17;

    hipMemsetAsync(cntr, 0, 4, stream);
    gate_convert<<<4096 + 6144, 256, 0, stream>>>(x, Wg, idxb, top1, xb, Wqkv, wb, ord, hs, cntr);
    qkv_gemm<<<512 + 2048, 256, 0, stream>>>(xb, wb, qbuf, ord, hs, top1, kshB, vshT);
    attn_mfma<<<1024, 256, 0, stream>>>(qbuf, kshB, vshT, y);
}

// Round 11
// 274.349 us; speedup vs baseline: 1.5839x; 1.5839x over previous
//
#include <hip/hip_runtime.h>
#include <math.h>
#include <cstddef>

// Problem constants
#define BB 2
#define TT 2048
#define CC 2048
#define HH 16
#define HD 128
#define MM (BB * TT)   // 4096 tokens
#define QKV_N 6144
#define BK 32

typedef __attribute__((ext_vector_type(8))) short short8;
typedef __attribute__((ext_vector_type(4))) float f32x4;

__device__ __forceinline__ unsigned short f2bf(float f) {
    union { float f; unsigned int u; } v; v.f = f;
    unsigned int r = v.u + 0x7FFFu + ((v.u >> 16) & 1u);  // RNE
    return (unsigned short)(r >> 16);
}
// 2-op nearest-half-up convert for the attn exp path (P > 0 always).
// R14's v_cvt_pk_bf16_f32 TRUNCATES on gfx950 (absmax 0.07) — do not use.
__device__ __forceinline__ unsigned short f2bf_up(float f) {
    union { float f; unsigned int u; } v; v.f = f;
    return (unsigned short)((v.u + 0x8000u) >> 16);
}
__device__ __forceinline__ float bf2f(unsigned short s) {
    union { unsigned int u; float f; } v; v.u = ((unsigned int)s) << 16;
    return v.f;
}
__device__ __forceinline__ void gload16(const void* g, void* l) {
    __builtin_amdgcn_global_load_lds(
        (const __attribute__((address_space(1))) unsigned int*)g,
        (__attribute__((address_space(3))) unsigned int*)l, 16, 0, 0);
}

// ---------------------------------------------------------------------------
// K1': fused gate + W_qkv convert (R18-validated). R19's last-block bucket
// fusion REVERTED: its per-block __threadfence() emits a device-scope L2
// writeback on gfx950 (non-coherent XCD L2s) -> 4096 serialized cache
// flushes inside a streaming kernel, 35 -> 234 µs. Never fence per-block.
// ---------------------------------------------------------------------------
__global__ __launch_bounds__(256) void gate_convert(const float* __restrict__ x,
                                                    const float* __restrict__ Wg,
                                                    int* __restrict__ idxbuf,
                                                    float* __restrict__ top1buf,
                                                    unsigned short* __restrict__ xb,
                                                    const float* __restrict__ Wqkv,
                                                    unsigned short* __restrict__ wb) {
    int tid = threadIdx.x;
    if (blockIdx.x >= 4096) {
        // ---- convert path ----
        int i = (blockIdx.x - 4096) * 256 + tid;
        int n8 = QKV_N * CC / 8;
        if (i >= n8) return;
        const float4* s4 = (const float4*)Wqkv;
        float4 a = s4[i * 2], b = s4[i * 2 + 1];
        union { unsigned short s[8]; uint4 u; } pk;
        pk.s[0] = f2bf(a.x); pk.s[1] = f2bf(a.y); pk.s[2] = f2bf(a.z); pk.s[3] = f2bf(a.w);
        pk.s[4] = f2bf(b.x); pk.s[5] = f2bf(b.y); pk.s[6] = f2bf(b.z); pk.s[7] = f2bf(b.w);
        ((uint4*)wb)[i] = pk.u;
        return;
    }
    // ---- gate path ----
    int m = blockIdx.x;
    int h = tid >> 4;
    int j = tid & 15;
    const float4* xr = (const float4*)(x + (size_t)m * CC);
    const float4* wr = (const float4*)(Wg + (size_t)h * CC);
    float acc = 0.f;
#pragma unroll 8
    for (int i = 0; i < CC / 4; i += 16) {
        float4 a = xr[i + j];
        float4 b = wr[i + j];
        acc += a.x * b.x + a.y * b.y + a.z * b.z + a.w * b.w;
    }
    for (int off = 8; off > 0; off >>= 1) acc += __shfl_down(acc, off, 16);
    __shared__ float logits[HH];
    if (j == 0) logits[h] = acc;
    // fused bf16 conversion of this token row (L1-hot re-read)
    {
        float4 a = xr[tid * 2], b = xr[tid * 2 + 1];
        union { unsigned short s[8]; uint4 u; } pk;
        pk.s[0] = f2bf(a.x); pk.s[1] = f2bf(a.y); pk.s[2] = f2bf(a.z); pk.s[3] = f2bf(a.w);
        pk.s[4] = f2bf(b.x); pk.s[5] = f2bf(b.y); pk.s[6] = f2bf(b.z); pk.s[7] = f2bf(b.w);
        ((uint4*)(xb + (size_t)m * CC))[tid] = pk.u;
    }
    __syncthreads();
    if (tid == 0) {
        float zmax = logits[0];
        int best = 0;
        for (int i = 1; i < HH; i++) {
            if (logits[i] > zmax) { zmax = logits[i]; best = i; }
        }
        float s = 0.f;
        for (int i = 0; i < HH; i++) s += expf(logits[i] - zmax);
        idxbuf[m] = best;
        top1buf[m] = 1.0f / s;
    }
}

// ---------------------------------------------------------------------------
// K4: bucket tokens by selected head (one block). Restored standalone
// (R19's in-kernel fusion regressed 200 µs via per-block threadfence).
// ---------------------------------------------------------------------------
__global__ __launch_bounds__(256) void bucket_kernel(const int* __restrict__ idxb,
                                                     int* __restrict__ ord,
                                                     int* __restrict__ hs) {
    __shared__ unsigned short cnts[256][16];
    __shared__ int hsum[16], hbase[16];
    int t = threadIdx.x;
    unsigned short c[16];
#pragma unroll
    for (int h = 0; h < 16; h++) c[h] = 0;
    int hv[16];
#pragma unroll
    for (int i = 0; i < 16; i++) {
        hv[i] = idxb[t * 16 + i];
        c[hv[i]]++;
    }
#pragma unroll
    for (int h = 0; h < 16; h++) cnts[t][h] = c[h];
    __syncthreads();
    if (t < 16) {
        int s = 0;
        for (int j = 0; j < 256; j++) {
            int v = cnts[j][t];
            cnts[j][t] = (unsigned short)s;
            s += v;
        }
        hsum[t] = s;
    }
    __syncthreads();
    if (t == 0) {
        int s = 0;
        for (int h = 0; h < 16; h++) { hbase[h] = s; hs[h] = s; s += hsum[h]; }
        hs[16] = s;
    }
    __syncthreads();
    int pos[16];
#pragma unroll
    for (int h = 0; h < 16; h++) pos[h] = hbase[h] + (int)cnts[t][h];
#pragma unroll
    for (int i = 0; i < 16; i++) {
        int h = hv[i];
        ord[pos[h]++] = t * 16 + i;
    }
}

// ---------------------------------------------------------------------------
// K3': fused qproj + kvsel GEMMs (R18-validated). Blocks [0,512) = qproj
// tile; [512,2560) = kvsel slot. 2-phase double-buffered staging.
// ---------------------------------------------------------------------------
__global__ __launch_bounds__(256) void qkv_gemm(const unsigned short* __restrict__ A,   // xb [M][2048]
                                                const unsigned short* __restrict__ Bm,  // wb [6144][2048]
                                                unsigned short* __restrict__ C,         // qbuf [M][2048]
                                                const int* __restrict__ ord,
                                                const int* __restrict__ hs,
                                                const float* __restrict__ top1,
                                                unsigned short* __restrict__ kshB,
                                                unsigned short* __restrict__ vshT) {
    __shared__ unsigned short ShA[2][128 * BK];
    __shared__ unsigned short ShB[2][128 * BK];
    int tid = threadIdx.x;
    int wave = tid >> 6, lane = tid & 63;
    int l = lane & 15, g = lane >> 4;
    int flat = blockIdx.x;

    if (flat < 512) {
        // ================= qproj path =================
        int m0 = (flat >> 4) * 128, n0 = (flat & 15) * 128;
        int wr = wave >> 1, wc = wave & 1;

        f32x4 acc[4][4];
#pragma unroll
        for (int i = 0; i < 4; i++)
#pragma unroll
            for (int j = 0; j < 4; j++) acc[i][j] = (f32x4){0.f, 0.f, 0.f, 0.f};

        int srow = lane >> 2;
        int scol = (lane & 3) * 8;
        const unsigned short* aB0 = A + (size_t)(m0 + wave * 32 + srow) * 2048 + scol;
        const unsigned short* bB0 = Bm + (size_t)(n0 + wave * 32 + srow) * 2048 + scol;

#define QSTAGE(k0_, bi) do {                                                    \
        gload16(aB0 + (k0_), &ShA[bi][wave * 1024]);                            \
        gload16(aB0 + (k0_) + (size_t)16 * 2048, &ShA[bi][wave * 1024 + 512]);  \
        gload16(bB0 + (k0_), &ShB[bi][wave * 1024]);                            \
        gload16(bB0 + (k0_) + (size_t)16 * 2048, &ShB[bi][wave * 1024 + 512]);  \
    } while (0)

        QSTAGE(0, 0);
        __syncthreads();

        for (int k0 = 0; k0 < 2048; k0 += BK) {
            int cur = (k0 >> 5) & 1;
            if (k0 + BK < 2048) QSTAGE(k0 + BK, cur ^ 1);
            short8 af[4], bf[4];
#pragma unroll
            for (int i = 0; i < 4; i++)
                af[i] = *(const short8*)&ShA[cur][(wr * 64 + i * 16 + l) * BK + g * 8];
#pragma unroll
            for (int j = 0; j < 4; j++)
                bf[j] = *(const short8*)&ShB[cur][(wc * 64 + j * 16 + l) * BK + g * 8];
#pragma unroll
            for (int i = 0; i < 4; i++)
#pragma unroll
                for (int j = 0; j < 4; j++)
                    acc[i][j] = __builtin_amdgcn_mfma_f32_16x16x32_bf16(af[i], bf[j], acc[i][j], 0, 0, 0);
            __syncthreads();
        }
#undef QSTAGE

        const float qscale = 0.08838834764831845f;  // 1/sqrt(128)
#pragma unroll
        for (int j = 0; j < 4; j++) {
            int col = n0 + wc * 64 + j * 16 + l;
#pragma unroll
            for (int i = 0; i < 4; i++) {
                int row = m0 + wr * 64 + i * 16 + g * 4;
#pragma unroll
                for (int r = 0; r < 4; r++)
                    C[(size_t)(row + r) * CC + col] = f2bf(acc[i][j][r] * qscale);
            }
        }
        return;
    }

    // ================= kvsel path =================
    {
        int kv = flat - 512;
        int h = kv & 15, reg = (kv >> 4) & 1, mt = kv >> 5;
        int s0 = hs[h], s1 = hs[h + 1];
        int cnt = s1 - s0;
        if (mt * 64 >= cnt) return;
        int base = s0 + mt * 64;

        int arow = base + wave * 16 + (lane >> 2);
        int atok = ord[(arow < s1) ? arow : (s1 - 1)];
        const unsigned short* aSrc = A + (size_t)atok * CC + (lane & 3) * 8;
        int wr0 = 2048 + reg * 2048 + h * 128;
        const unsigned short* bSrc0 = Bm + (size_t)(wr0 + (wave * 2 + 0) * 16 + (lane >> 2)) * CC + (lane & 3) * 8;
        const unsigned short* bSrc1 = Bm + (size_t)(wr0 + (wave * 2 + 1) * 16 + (lane >> 2)) * CC + (lane & 3) * 8;

#define KSTAGE(k0_, bi) do {                                      \
        gload16(aSrc + (k0_), &ShA[bi][wave * 512]);              \
        gload16(bSrc0 + (k0_), &ShB[bi][(wave * 2 + 0) * 512]);   \
        gload16(bSrc1 + (k0_), &ShB[bi][(wave * 2 + 1) * 512]);   \
    } while (0)

        f32x4 acc[8];
#pragma unroll
        for (int j = 0; j < 8; j++) acc[j] = (f32x4){0.f, 0.f, 0.f, 0.f};

        KSTAGE(0, 0);
        __syncthreads();

        for (int k0 = 0; k0 < 2048; k0 += 32) {
            int cur = (k0 >> 5) & 1;
            if (k0 + 32 < 2048) KSTAGE(k0 + 32, cur ^ 1);
            short8 af = *(const short8*)&ShA[cur][(wave * 16 + l) * 32 + g * 8];
#pragma unroll
            for (int j = 0; j < 8; j++) {
                short8 bf = *(const short8*)&ShB[cur][(j * 16 + l) * 32 + g * 8];
                acc[j] = __builtin_amdgcn_mfma_f32_16x16x32_bf16(af, bf, acc[j], 0, 0, 0);
            }
            __syncthreads();
        }
#undef KSTAGE

#pragma unroll
        for (int i = 0; i < 4; i++) {
            int r = wave * 16 + g * 4 + i;
            if (base + r >= s1) continue;
            int tok = ord[base + r];
            if (reg == 0) {
#pragma unroll
                for (int j = 0; j < 8; j++)
                    kshB[(size_t)tok * HD + j * 16 + l] = f2bf(acc[j][i]);
            } else {
                float tv = top1[tok];
#pragma unroll
                for (int j = 0; j < 8; j++)
                    vshT[(size_t)(j * 16 + l) * MM + tok] = f2bf(acc[j][i] * tv);
            }
        }
    }
}

// ---------------------------------------------------------------------------
// K6: MFMA bf16 flash attention — R17 structure (unpaired q-tiles, 1024
// blocks, 4 blocks/CU) + T5 setprio around MFMA clusters (R19's only
// salvageable change, now measured in isolation vs R18's 73 µs).
// ---------------------------------------------------------------------------
__global__ __launch_bounds__(256, 4) void attn_mfma(const unsigned short* __restrict__ qb,   // [M][2048] bf16, q pre-scaled
                                                    const unsigned short* __restrict__ kb,   // [M][128] bf16
                                                    const unsigned short* __restrict__ vtb,  // [128][M] bf16
                                                    float* __restrict__ y) {                 // [M][2048] fp32
    __shared__ unsigned short KsA[2][32 * 128];   // 16384 B, linear, swizzled content
    __shared__ unsigned short VtA[2][128 * 32];   // 16384 B, linear, swizzled content
    __shared__ unsigned short Ps[4][16][40];      // 5120 B (per-wave)

    int bid = blockIdx.x;                 // 1024 blocks
    // boustrophedon descending-workload rank
    int t = bid & 255, r = bid >> 8;
    int k = (r << 8) | ((r & 1) ? (255 - t) : t);
    int qi = 127 - (k >> 3);              // q-tile 127..0 (long first)
    int b  = (k >> 2) & 1;
    int hq = k & 3;                       // head quarter
    int q0 = qi * 16;
    int nch = (qi >> 1) + 1;              // 1..64 32-key chunks
    int tid = threadIdx.x;
    int wave = tid >> 6;
    int lane = tid & 63;
    int l = lane & 15;
    int g = lane >> 4;
    int h = hq * 4 + wave;                // one head per wave

    // Q a-frags (bf16, pre-scaled)
    short8 qf[4];
    {
        const unsigned short* qrow = qb + (size_t)(b * TT + q0 + l) * CC + h * HD;
#pragma unroll
        for (int kc = 0; kc < 4; kc++)
            qf[kc] = *(const short8*)(qrow + kc * 32 + g * 8);
    }

    // ones-column B-frag: B[n][k] = (n==0) ? 1 : 0
    short8 onesf;
    {
        short v = (l == 0) ? (short)0x3F80 : (short)0;
#pragma unroll
        for (int e = 0; e < 8; e++) onesf[e] = v;
    }

    f32x4 o[8];
    f32x4 o8 = (f32x4){0.f, 0.f, 0.f, 0.f};
#pragma unroll
    for (int n = 0; n < 8; n++) o[n] = (f32x4){0.f, 0.f, 0.f, 0.f};

    const unsigned short* kbase = kb + (size_t)b * TT * HD;
    int rbase = q0 + g * 4;

    // Staging: 512 16B slots each for K and V; thread stages slots tid, tid+256.
    // K slot s: row r=s>>4 (key), physical chunk p=s&15; holds global chunk p^(r&15).
    // V slot s: row d=s>>2 (dim), physical chunk p=s&3; holds global chunk p^((d>>1)&3).
    // global_load_lds writes lane i at (uniform base + i*16) -> linear slot order.
#define STAGE(cc, bufi) do {                                                      \
        int kc0_ = (cc) * 32;                                                     \
        _Pragma("unroll")                                                         \
        for (int rep_ = 0; rep_ < 2; rep_++) {                                    \
            int s_ = tid + rep_ * 256;                                            \
            int kr_ = s_ >> 4, kp_ = s_ & 15;                                     \
            gload16(kbase + (size_t)(kc0_ + kr_) * HD + ((kp_ ^ (kr_ & 15)) * 8), \
                    &KsA[bufi][(rep_ * 256 + wave * 64) * 8]);                    \
            int vd_ = s_ >> 2, vp_ = s_ & 3;                                      \
            int vq_ = vp_ ^ ((vd_ >> 1) & 3);                                     \
            gload16(vtb + (size_t)vd_ * MM + b * TT + kc0_ + vq_ * 8,             \
                    &VtA[bufi][(rep_ * 256 + wave * 64) * 8]);                    \
        }                                                                         \
    } while (0)

    STAGE(0, 0);
    __syncthreads();   // drains the prologue staging (vmcnt(0) inside)

    for (int c = 0; c < nch; c++) {
        int kc0 = c * 32;
        int cur = c & 1;
        if (c + 1 < nch) STAGE(c + 1, cur ^ 1);   // prefetch flies during compute
        bool diag = (c == nch - 1);
        const unsigned short* Kc = KsA[cur];
        const unsigned short* Vc = VtA[cur];

        // S = Q K^T over 2 key-tiles of 16.
#pragma unroll
        for (int tt = 0; tt < 2; tt++) {
            short8 kf[4];
#pragma unroll
            for (int kc = 0; kc < 4; kc++)
                kf[kc] = *(const short8*)&Kc[(tt * 16 + l) * 128 + (((kc * 4 + g) ^ l) * 8)];
            f32x4 sl = (f32x4){0.f, 0.f, 0.f, 0.f};
            __builtin_amdgcn_s_setprio(1);
#pragma unroll
            for (int kc = 0; kc < 4; kc++)
                sl = __builtin_amdgcn_mfma_f32_16x16x32_bf16(qf[kc], kf[kc], sl, 0, 0, 0);
            __builtin_amdgcn_s_setprio(0);
            if (diag) {
                int key = kc0 + tt * 16 + l;
#pragma unroll
                for (int i = 0; i < 4; i++)
                    if (key > rbase + i) sl[i] = -1e30f;
            }
#pragma unroll
            for (int i = 0; i < 4; i++)
                Ps[wave][g * 4 + i][tt * 16 + l] = f2bf_up(__expf(sl[i] - 30.f));
        }
        // O += P V ; l += P.
        {
            short8 pf0 = *(const short8*)&Ps[wave][l][g * 8];
            __builtin_amdgcn_s_setprio(1);
#pragma unroll
            for (int n = 0; n < 8; n++) {
                short8 vf = *(const short8*)&Vc[(n * 16 + l) * 32 + ((g ^ ((l >> 1) & 3)) * 8)];
                o[n] = __builtin_amdgcn_mfma_f32_16x16x32_bf16(pf0, vf, o[n], 0, 0, 0);
            }
            o8 = __builtin_amdgcn_mfma_f32_16x16x32_bf16(pf0, onesf, o8, 0, 0, 0);
            __builtin_amdgcn_s_setprio(0);
        }
        __syncthreads();   // vmcnt(0)+lgkmcnt(0) drain AFTER compute: prefetch done,
                           // and all waves finished reading buf[cur] before next overwrite
    }
#undef STAGE

    // epilogue: normalize; l for row g*4+i sits in lane (g*16, reg i)
    {
        float inv[4];
#pragma unroll
        for (int i = 0; i < 4; i++) {
            float lv = __shfl(o8[i], lane & 48);
            inv[i] = 1.f / lv;
        }
#pragma unroll
        for (int n = 0; n < 8; n++) {
#pragma unroll
            for (int i = 0; i < 4; i++) {
                y[(size_t)(b * TT + q0 + g * 4 + i) * CC + h * HD + n * 16 + l] =
                    o[n][i] * inv[i];
            }
        }
    }
}

// ---------------------------------------------------------------------------
// Launcher. Workspace (~62 MB). 4 launches (R18 structure restored).
// ---------------------------------------------------------------------------
extern "C" void kernel_launch(void* const* d_in, const int* in_sizes, int n_in,
                              void* d_out, int out_size, void* d_ws, size_t ws_size,
                              hipStream_t stream) {
    (void)in_sizes; (void)n_in; (void)out_size; (void)ws_size;
    const float* x    = (const float*)d_in[0];
    const float* Wg   = (const float*)d_in[1];
    const float* Wqkv = (const float*)d_in[2];
    float* y = (float*)d_out;

    unsigned short* xb   = (unsigned short*)d_ws;
    unsigned short* wb   = xb + (size_t)MM * CC;
    unsigned short* qbuf = wb + (size_t)QKV_N * CC;
    unsigned short* kshB = qbuf + (size_t)MM * CC;
    unsigned short* vshT = kshB + (size_t)MM * HD;
    float* top1 = (float*)(vshT + (size_t)HD * MM);
    int*   idxb = (int*)(top1 + MM);
    int*   ord  = idxb + MM;
    int*   hs   = ord + MM;

    gate_convert<<<4096 + 6144, 256, 0, stream>>>(x, Wg, idxb, top1, xb, Wqkv, wb);
    bucket_kernel<<<1, 256, 0, stream>>>(idxb, ord, hs);
    qkv_gemm<<<512 + 2048, 256, 0, stream>>>(xb, wb, qbuf, ord, hs, top1, kshB, vshT);
    attn_mfma<<<1024, 256, 0, stream>>>(qbuf, kshB, vshT, y);
}